// Round 1
// baseline (105.926 us; speedup 1.0000x reference)
//
#include <hip/hip_runtime.h>

#define N_ROWS 4096
#define D_DIM  512
#define C_ROWS 8192

typedef __attribute__((ext_vector_type(8))) short bfrag8;   // 8 bf16 (4 VGPRs)
typedef __attribute__((ext_vector_type(4))) float f32x4;    // MFMA acc
typedef __attribute__((ext_vector_type(8))) unsigned short ushort8;

#define AS1 __attribute__((address_space(1)))
#define AS3 __attribute__((address_space(3)))

__device__ __forceinline__ void gload_lds16(const void* g, void* l) {
    __builtin_amdgcn_global_load_lds((const AS1 unsigned int*)g,
                                     (AS3 unsigned int*)l, 16, 0, 0);
}

__device__ __forceinline__ unsigned short f2bf(float f) {
    unsigned int u = __float_as_uint(f);
    unsigned int r = (u + 0x7fffu + ((u >> 16) & 1u)) >> 16;   // RNE
    return (unsigned short)r;
}
__device__ __forceinline__ float bf2f(unsigned short h) {
    return __uint_as_float(((unsigned int)h) << 16);
}

// ---------------- init: zero accumulators ----------------
__global__ void init_kernel(float* lossAcc, unsigned int* cntAcc) {
    if (threadIdx.x == 0) { lossAcc[0] = 0.0f; cntAcc[0] = 0u; }
}

// ---------------- l2-normalize rows, fp32 -> bf16 ----------------
// one wave per row of D=512; block = 256 threads = 4 rows
__global__ __launch_bounds__(256) void normalize_kernel(
        const float* __restrict__ src, unsigned short* __restrict__ dst, int rows) {
    const int w    = threadIdx.x >> 6;
    const int lane = threadIdx.x & 63;
    const int row  = blockIdx.x * 4 + w;
    if (row >= rows) return;

    const float* r = src + (size_t)row * D_DIM + lane * 8;
    float4 v0 = *(const float4*)(r);
    float4 v1 = *(const float4*)(r + 4);
    float ss = v0.x*v0.x + v0.y*v0.y + v0.z*v0.z + v0.w*v0.w
             + v1.x*v1.x + v1.y*v1.y + v1.z*v1.z + v1.w*v1.w;
    #pragma unroll
    for (int off = 32; off; off >>= 1) ss += __shfl_xor(ss, off);
    const float nrm = sqrtf(ss);
    const float sc  = 1.0f / fmaxf(nrm, 1e-12f);

    ushort8 pk;
    pk[0] = f2bf(v0.x * sc); pk[1] = f2bf(v0.y * sc);
    pk[2] = f2bf(v0.z * sc); pk[3] = f2bf(v0.w * sc);
    pk[4] = f2bf(v1.x * sc); pk[5] = f2bf(v1.y * sc);
    pk[6] = f2bf(v1.z * sc); pk[7] = f2bf(v1.w * sc);
    *(ushort8*)(dst + (size_t)row * D_DIM + lane * 8) = pk;
}

// ---------------- pos_dot[i] = fN[i] . cN[labels[i]] ----------------
__global__ __launch_bounds__(256) void posdot_kernel(
        const unsigned short* __restrict__ fN, const unsigned short* __restrict__ cN,
        const int* __restrict__ labels, float* __restrict__ pos) {
    const int w    = threadIdx.x >> 6;
    const int lane = threadIdx.x & 63;
    const int i    = blockIdx.x * 4 + w;
    const int lab  = labels[i];

    ushort8 a = *(const ushort8*)(fN + (size_t)i   * D_DIM + lane * 8);
    ushort8 b = *(const ushort8*)(cN + (size_t)lab * D_DIM + lane * 8);
    float s = 0.0f;
    #pragma unroll
    for (int t = 0; t < 8; ++t) s += bf2f(a[t]) * bf2f(b[t]);
    #pragma unroll
    for (int off = 32; off; off >>= 1) s += __shfl_xor(s, off);
    if (lane == 0) pos[i] = s;
}

// ---------------- fused GEMM + masked softplus reduction ----------------
// S = fN . cN^T  tile 128x128, BK=32, 4 waves (2x2), mfma 16x16x32 bf16
__global__ __launch_bounds__(256) void fused_loss_kernel(
        const unsigned short* __restrict__ fN, const unsigned short* __restrict__ cN,
        const int* __restrict__ labels, const float* __restrict__ pos,
        float* __restrict__ lossAcc, unsigned int* __restrict__ cntAcc) {
    __shared__ unsigned short As[128 * 32];   // [row][k], 8 KB
    __shared__ unsigned short Bs[128 * 32];   // [col][k], 8 KB
    __shared__ float    s_sum[4];
    __shared__ unsigned s_cnt[4];

    const int w    = threadIdx.x >> 6;
    const int lane = threadIdx.x & 63;
    const int wr   = w >> 1;          // wave row (0..1)
    const int wc   = w & 1;           // wave col (0..1)
    const int rowBase = blockIdx.y * 128;
    const int colBase = blockIdx.x * 128;

    const int lr = lane & 15;         // frag row (A) / frag col (B)
    const int kq = lane >> 4;         // k quad

    // staging geometry: issue q of wave w covers LDS bytes [(w*2+q)*1024, +1024)
    const int chunk0 = w * 2;
    const int srow0  = chunk0 * 16 + (lane >> 2);     // tile row for issue 0
    const int srow1  = srow0 + 16;                    // tile row for issue 1
    const int scol   = (lane & 3) * 8;                // k offset within BK

    f32x4 acc[4][4] = {};

    for (int kt = 0; kt < 16; ++kt) {
        const int K0 = kt * 32;
        // ---- stage A,B tiles (global -> LDS, 16B per lane per issue) ----
        gload_lds16(fN + (size_t)(rowBase + srow0) * D_DIM + K0 + scol,
                    &As[(chunk0 + 0) * 512]);
        gload_lds16(fN + (size_t)(rowBase + srow1) * D_DIM + K0 + scol,
                    &As[(chunk0 + 1) * 512]);
        gload_lds16(cN + (size_t)(colBase + srow0) * D_DIM + K0 + scol,
                    &Bs[(chunk0 + 0) * 512]);
        gload_lds16(cN + (size_t)(colBase + srow1) * D_DIM + K0 + scol,
                    &Bs[(chunk0 + 1) * 512]);
        __syncthreads();

        // ---- fragments + 16 MFMA ----
        bfrag8 af[4], bb[4];
        #pragma unroll
        for (int m = 0; m < 4; ++m)
            af[m] = *(const bfrag8*)&As[(wr * 64 + m * 16 + lr) * 32 + kq * 8];
        #pragma unroll
        for (int n = 0; n < 4; ++n)
            bb[n] = *(const bfrag8*)&Bs[(wc * 64 + n * 16 + lr) * 32 + kq * 8];
        #pragma unroll
        for (int m = 0; m < 4; ++m)
            #pragma unroll
            for (int n = 0; n < 4; ++n)
                acc[m][n] = __builtin_amdgcn_mfma_f32_16x16x32_bf16(
                                af[m], bb[n], acc[m][n], 0, 0, 0);
        __syncthreads();
    }

    // ---- epilogue: x = S_ij - pos[i]; mask j != label[i]; softplus; sum ----
    float lsum = 0.0f;
    unsigned cnt = 0;
    #pragma unroll
    for (int m = 0; m < 4; ++m) {
        #pragma unroll
        for (int j = 0; j < 4; ++j) {
            const int gi = rowBase + wr * 64 + m * 16 + kq * 4 + j;
            const float p = pos[gi];
            const int lab = labels[gi];
            #pragma unroll
            for (int n = 0; n < 4; ++n) {
                const int gj = colBase + wc * 64 + n * 16 + lr;
                const float x = acc[m][n][j] - p;
                if (gj != lab) {
                    const float l = __logf(1.0f + __expf(x));   // softplus, x in [-2.2,2.2]
                    if (l > 0.0f) { lsum += l; cnt++; }
                }
            }
        }
    }
    #pragma unroll
    for (int off = 32; off; off >>= 1) {
        lsum += __shfl_xor(lsum, off);
        cnt  += __shfl_xor(cnt,  off);
    }
    if (lane == 0) { s_sum[w] = lsum; s_cnt[w] = cnt; }
    __syncthreads();
    if (threadIdx.x == 0) {
        atomicAdd(lossAcc, s_sum[0] + s_sum[1] + s_sum[2] + s_sum[3]);
        atomicAdd(cntAcc,  s_cnt[0] + s_cnt[1] + s_cnt[2] + s_cnt[3]);
    }
}

// ---------------- finalize ----------------
__global__ void finalize_kernel(const float* lossAcc, const unsigned int* cntAcc,
                                float* out) {
    if (threadIdx.x == 0) {
        const float l = lossAcc[0];
        const unsigned c = cntAcc[0];
        out[0] = (c > 0u) ? l / (float)c : l;
    }
}

extern "C" void kernel_launch(void* const* d_in, const int* in_sizes, int n_in,
                              void* d_out, int out_size, void* d_ws, size_t ws_size,
                              hipStream_t stream) {
    const float* features = (const float*)d_in[0];   // [4096, 512]
    const float* centers  = (const float*)d_in[1];   // [8192, 512]
    const int*   labels   = (const int*)d_in[2];     // [4096]
    float* out = (float*)d_out;

    char* ws = (char*)d_ws;
    unsigned short* fN  = (unsigned short*)ws;                       // 4 MB
    unsigned short* cN  = (unsigned short*)(ws + (4u << 20));        // 8 MB
    float*          pos = (float*)(ws + (12u << 20));                // 16 KB
    float*          lossAcc = (float*)(ws + (12u << 20) + (1u << 16));
    unsigned int*   cntAcc  = (unsigned int*)(lossAcc + 1);

    init_kernel<<<1, 64, 0, stream>>>(lossAcc, cntAcc);
    normalize_kernel<<<N_ROWS / 4, 256, 0, stream>>>(features, fN, N_ROWS);
    normalize_kernel<<<C_ROWS / 4, 256, 0, stream>>>(centers,  cN, C_ROWS);
    posdot_kernel<<<N_ROWS / 4, 256, 0, stream>>>(fN, cN, labels, pos);

    dim3 grid(C_ROWS / 128, N_ROWS / 128);   // 64 x 32 = 2048 blocks
    fused_loss_kernel<<<grid, 256, 0, stream>>>(fN, cN, labels, pos, lossAcc, cntAcc);

    finalize_kernel<<<1, 64, 0, stream>>>(lossAcc, cntAcc, out);
}

// Round 2
// 100.646 us; speedup vs baseline: 1.0525x; 1.0525x over previous
//
#include <hip/hip_runtime.h>

#define N_ROWS 4096
#define D_DIM  512
#define C_ROWS 8192
#define NBLK   ((N_ROWS / 128) * (C_ROWS / 128))   // 2048

typedef __attribute__((ext_vector_type(8))) short bfrag8;   // 8 bf16 (4 VGPRs)
typedef __attribute__((ext_vector_type(4))) float f32x4;    // MFMA acc
typedef __attribute__((ext_vector_type(8))) unsigned short ushort8;

#define AS1 __attribute__((address_space(1)))
#define AS3 __attribute__((address_space(3)))

__device__ __forceinline__ void gload_lds16(const void* g, void* l) {
    __builtin_amdgcn_global_load_lds((const AS1 unsigned int*)g,
                                     (AS3 unsigned int*)l, 16, 0, 0);
}

__device__ __forceinline__ unsigned short f2bf(float f) {
    unsigned int u = __float_as_uint(f);
    unsigned int r = (u + 0x7fffu + ((u >> 16) & 1u)) >> 16;   // RNE
    return (unsigned short)r;
}
__device__ __forceinline__ float bf2f(unsigned short h) {
    return __uint_as_float(((unsigned int)h) << 16);
}

// ---------------- l2-normalize rows, fp32 -> bf16 ----------------
// one wave per row of D=512; block = 256 threads = 4 rows
__global__ __launch_bounds__(256) void normalize_kernel(
        const float* __restrict__ src, unsigned short* __restrict__ dst, int rows) {
    const int w    = threadIdx.x >> 6;
    const int lane = threadIdx.x & 63;
    const int row  = blockIdx.x * 4 + w;
    if (row >= rows) return;

    const float* r = src + (size_t)row * D_DIM + lane * 8;
    float4 v0 = *(const float4*)(r);
    float4 v1 = *(const float4*)(r + 4);
    float ss = v0.x*v0.x + v0.y*v0.y + v0.z*v0.z + v0.w*v0.w
             + v1.x*v1.x + v1.y*v1.y + v1.z*v1.z + v1.w*v1.w;
    #pragma unroll
    for (int off = 32; off; off >>= 1) ss += __shfl_xor(ss, off);
    const float nrm = sqrtf(ss);
    const float sc  = 1.0f / fmaxf(nrm, 1e-12f);

    ushort8 pk;
    pk[0] = f2bf(v0.x * sc); pk[1] = f2bf(v0.y * sc);
    pk[2] = f2bf(v0.z * sc); pk[3] = f2bf(v0.w * sc);
    pk[4] = f2bf(v1.x * sc); pk[5] = f2bf(v1.y * sc);
    pk[6] = f2bf(v1.z * sc); pk[7] = f2bf(v1.w * sc);
    *(ushort8*)(dst + (size_t)row * D_DIM + lane * 8) = pk;
}

// ---------------- pos_dot[i] = fN[i] . cN[labels[i]] ----------------
__global__ __launch_bounds__(256) void posdot_kernel(
        const unsigned short* __restrict__ fN, const unsigned short* __restrict__ cN,
        const int* __restrict__ labels, float* __restrict__ pos) {
    const int w    = threadIdx.x >> 6;
    const int lane = threadIdx.x & 63;
    const int i    = blockIdx.x * 4 + w;
    const int lab  = labels[i];

    ushort8 a = *(const ushort8*)(fN + (size_t)i   * D_DIM + lane * 8);
    ushort8 b = *(const ushort8*)(cN + (size_t)lab * D_DIM + lane * 8);
    float s = 0.0f;
    #pragma unroll
    for (int t = 0; t < 8; ++t) s += bf2f(a[t]) * bf2f(b[t]);
    #pragma unroll
    for (int off = 32; off; off >>= 1) s += __shfl_xor(s, off);
    if (lane == 0) pos[i] = s;
}

// ---------------- fused GEMM + masked softplus reduction ----------------
// S = fN . cN^T  tile 128x128, BK=32, 4 waves (2x2), mfma 16x16x32 bf16
// double-buffered LDS (2-phase), XOR-swizzled LDS layout (both-sides):
//   LDS slot s of row r holds global k-segment (s ^ ((r>>1)&3))  [16B segs]
__global__ __launch_bounds__(256) void fused_loss_kernel(
        const unsigned short* __restrict__ fN, const unsigned short* __restrict__ cN,
        const int* __restrict__ labels, const float* __restrict__ pos,
        float* __restrict__ partialL, unsigned int* __restrict__ partialC) {
    __shared__ unsigned short As[2][128 * 32];   // 16 KB
    __shared__ unsigned short Bs[2][128 * 32];   // 16 KB
    __shared__ float    s_sum[4];
    __shared__ unsigned s_cnt[4];

    const int w    = threadIdx.x >> 6;
    const int lane = threadIdx.x & 63;
    const int wr   = w >> 1;          // wave row (0..1)
    const int wc   = w & 1;           // wave col (0..1)
    const int rowBase = blockIdx.y * 128;
    const int colBase = blockIdx.x * 128;

    const int lr  = lane & 15;        // frag row (A) / frag col (B)
    const int kq  = lane >> 4;        // k quad (16B slot, pre-swizzle)
    const int kqs = kq ^ ((lr >> 1) & 3);   // swizzled 16B slot for reads

    // staging geometry: issue q of wave w covers LDS bytes [(w*2+q)*1024, +1024)
    const int chunk0 = w * 2;
    const int srow0  = chunk0 * 16 + (lane >> 2);     // tile row for issue 0
    const int srow1  = srow0 + 16;                    // tile row for issue 1
    // pre-swizzled global k-segment for this lane (involution of LDS slot l&3)
    const int scol   = (((lane & 3) ^ ((lane >> 3) & 3)) * 8);

    const unsigned short* aSrc0 = fN + (size_t)(rowBase + srow0) * D_DIM + scol;
    const unsigned short* aSrc1 = fN + (size_t)(rowBase + srow1) * D_DIM + scol;
    const unsigned short* bSrc0 = cN + (size_t)(colBase + srow0) * D_DIM + scol;
    const unsigned short* bSrc1 = cN + (size_t)(colBase + srow1) * D_DIM + scol;

    f32x4 acc[4][4] = {};

#define STAGE(buf, K0)                                                     \
    do {                                                                   \
        gload_lds16(aSrc0 + (K0), &As[buf][(chunk0 + 0) * 512]);           \
        gload_lds16(aSrc1 + (K0), &As[buf][(chunk0 + 1) * 512]);           \
        gload_lds16(bSrc0 + (K0), &Bs[buf][(chunk0 + 0) * 512]);           \
        gload_lds16(bSrc1 + (K0), &Bs[buf][(chunk0 + 1) * 512]);           \
    } while (0)

    // prologue: stage K-tile 0 into buffer 0
    STAGE(0, 0);
    __syncthreads();   // drains vmcnt -> buf0 ready

    #pragma unroll 4
    for (int kt = 0; kt < 16; ++kt) {
        const int cur = kt & 1;
        if (kt < 15) STAGE(1 - cur, (kt + 1) * 32);   // prefetch next tile

        // ---- fragments (swizzled read) + 16 MFMA ----
        bfrag8 af[4], bb[4];
        #pragma unroll
        for (int m = 0; m < 4; ++m)
            af[m] = *(const bfrag8*)&As[cur][(wr * 64 + m * 16 + lr) * 32 + kqs * 8];
        #pragma unroll
        for (int n = 0; n < 4; ++n)
            bb[n] = *(const bfrag8*)&Bs[cur][(wc * 64 + n * 16 + lr) * 32 + kqs * 8];
        #pragma unroll
        for (int m = 0; m < 4; ++m)
            #pragma unroll
            for (int n = 0; n < 4; ++n)
                acc[m][n] = __builtin_amdgcn_mfma_f32_16x16x32_bf16(
                                af[m], bb[n], acc[m][n], 0, 0, 0);

        // one barrier per iter: drains this iter's prefetch (vmcnt) and
        // guarantees all waves consumed buf[cur] before it is overwritten
        __syncthreads();
    }
#undef STAGE

    // ---- epilogue: x = S_ij - pos[i]; mask j != label[i]; softplus; sum ----
    float lsum = 0.0f;
    unsigned cnt = 0;
    #pragma unroll
    for (int m = 0; m < 4; ++m) {
        #pragma unroll
        for (int j = 0; j < 4; ++j) {
            const int gi = rowBase + wr * 64 + m * 16 + kq * 4 + j;
            const float p = pos[gi];
            const int lab = labels[gi];
            #pragma unroll
            for (int n = 0; n < 4; ++n) {
                const int gj = colBase + wc * 64 + n * 16 + lr;
                const float x = acc[m][n][j] - p;
                if (gj != lab) {
                    const float l = __logf(1.0f + __expf(x));   // softplus, x in [-2.2,2.2]
                    if (l > 0.0f) { lsum += l; cnt++; }
                }
            }
        }
    }
    #pragma unroll
    for (int off = 32; off; off >>= 1) {
        lsum += __shfl_xor(lsum, off);
        cnt  += __shfl_xor(cnt,  off);
    }
    if (lane == 0) { s_sum[w] = lsum; s_cnt[w] = cnt; }
    __syncthreads();
    if (threadIdx.x == 0) {
        const int bid = blockIdx.y * gridDim.x + blockIdx.x;
        partialL[bid] = s_sum[0] + s_sum[1] + s_sum[2] + s_sum[3];
        partialC[bid] = s_cnt[0] + s_cnt[1] + s_cnt[2] + s_cnt[3];
    }
}

// ---------------- finalize: reduce 2048 per-block partials ----------------
__global__ __launch_bounds__(256) void finalize_kernel(
        const float* __restrict__ partialL, const unsigned int* __restrict__ partialC,
        float* __restrict__ out) {
    __shared__ float    s_sum[4];
    __shared__ unsigned s_cnt[4];
    const int w    = threadIdx.x >> 6;
    const int lane = threadIdx.x & 63;

    float s = 0.0f; unsigned c = 0;
    for (int i = threadIdx.x; i < NBLK; i += 256) { s += partialL[i]; c += partialC[i]; }
    #pragma unroll
    for (int off = 32; off; off >>= 1) {
        s += __shfl_xor(s, off);
        c += __shfl_xor(c, off);
    }
    if (lane == 0) { s_sum[w] = s; s_cnt[w] = c; }
    __syncthreads();
    if (threadIdx.x == 0) {
        const float    l = s_sum[0] + s_sum[1] + s_sum[2] + s_sum[3];
        const unsigned n = s_cnt[0] + s_cnt[1] + s_cnt[2] + s_cnt[3];
        out[0] = (n > 0u) ? l / (float)n : l;
    }
}

extern "C" void kernel_launch(void* const* d_in, const int* in_sizes, int n_in,
                              void* d_out, int out_size, void* d_ws, size_t ws_size,
                              hipStream_t stream) {
    const float* features = (const float*)d_in[0];   // [4096, 512]
    const float* centers  = (const float*)d_in[1];   // [8192, 512]
    const int*   labels   = (const int*)d_in[2];     // [4096]
    float* out = (float*)d_out;

    char* ws = (char*)d_ws;
    unsigned short* fN  = (unsigned short*)ws;                        // 4 MB
    unsigned short* cN  = (unsigned short*)(ws + (4u << 20));         // 8 MB
    float*          pos = (float*)(ws + (12u << 20));                 // 16 KB
    float*          partialL = (float*)(ws + (12u << 20) + (1u << 16));        // 8 KB
    unsigned int*   partialC = (unsigned int*)(ws + (12u << 20) + (1u << 16) + (1u << 13)); // 8 KB

    normalize_kernel<<<N_ROWS / 4, 256, 0, stream>>>(features, fN, N_ROWS);
    normalize_kernel<<<C_ROWS / 4, 256, 0, stream>>>(centers,  cN, C_ROWS);
    posdot_kernel<<<N_ROWS / 4, 256, 0, stream>>>(fN, cN, labels, pos);

    dim3 grid(C_ROWS / 128, N_ROWS / 128);   // 64 x 32 = 2048 blocks
    fused_loss_kernel<<<grid, 256, 0, stream>>>(fN, cN, labels, pos, partialL, partialC);

    finalize_kernel<<<1, 256, 0, stream>>>(partialL, partialC, out);
}

// Round 3
// 85.569 us; speedup vs baseline: 1.2379x; 1.1762x over previous
//
#include <hip/hip_runtime.h>

#define N_ROWS 4096
#define D_DIM  512
#define C_ROWS 8192
#define NBLK   ((N_ROWS / 128) * (C_ROWS / 128))   // 2048

typedef __attribute__((ext_vector_type(8))) short bfrag8;   // 8 bf16 (4 VGPRs)
typedef __attribute__((ext_vector_type(4))) float f32x4;    // MFMA acc
typedef __attribute__((ext_vector_type(8))) unsigned short ushort8;

#define AS1 __attribute__((address_space(1)))
#define AS3 __attribute__((address_space(3)))

__device__ __forceinline__ void gload_lds16(const void* g, void* l) {
    __builtin_amdgcn_global_load_lds((const AS1 unsigned int*)g,
                                     (AS3 unsigned int*)l, 16, 0, 0);
}

__device__ __forceinline__ unsigned short f2bf(float f) {
    unsigned int u = __float_as_uint(f);
    unsigned int r = (u + 0x7fffu + ((u >> 16) & 1u)) >> 16;   // RNE
    return (unsigned short)r;
}
__device__ __forceinline__ float bf2f(unsigned short h) {
    return __uint_as_float(((unsigned int)h) << 16);
}

// ---------------- l2-normalize rows, fp32 -> bf16 ----------------
__global__ __launch_bounds__(256) void normalize_kernel(
        const float* __restrict__ src, unsigned short* __restrict__ dst, int rows) {
    const int w    = threadIdx.x >> 6;
    const int lane = threadIdx.x & 63;
    const int row  = blockIdx.x * 4 + w;
    if (row >= rows) return;

    const float* r = src + (size_t)row * D_DIM + lane * 8;
    float4 v0 = *(const float4*)(r);
    float4 v1 = *(const float4*)(r + 4);
    float ss = v0.x*v0.x + v0.y*v0.y + v0.z*v0.z + v0.w*v0.w
             + v1.x*v1.x + v1.y*v1.y + v1.z*v1.z + v1.w*v1.w;
    #pragma unroll
    for (int off = 32; off; off >>= 1) ss += __shfl_xor(ss, off);
    const float nrm = sqrtf(ss);
    const float sc  = 1.0f / fmaxf(nrm, 1e-12f);

    ushort8 pk;
    pk[0] = f2bf(v0.x * sc); pk[1] = f2bf(v0.y * sc);
    pk[2] = f2bf(v0.z * sc); pk[3] = f2bf(v0.w * sc);
    pk[4] = f2bf(v1.x * sc); pk[5] = f2bf(v1.y * sc);
    pk[6] = f2bf(v1.z * sc); pk[7] = f2bf(v1.w * sc);
    *(ushort8*)(dst + (size_t)row * D_DIM + lane * 8) = pk;
}

// ---------------- pos_dot[i] = fN[i] . cN[labels[i]] ----------------
__global__ __launch_bounds__(256) void posdot_kernel(
        const unsigned short* __restrict__ fN, const unsigned short* __restrict__ cN,
        const int* __restrict__ labels, float* __restrict__ pos) {
    const int w    = threadIdx.x >> 6;
    const int lane = threadIdx.x & 63;
    const int i    = blockIdx.x * 4 + w;
    const int lab  = labels[i];

    ushort8 a = *(const ushort8*)(fN + (size_t)i   * D_DIM + lane * 8);
    ushort8 b = *(const ushort8*)(cN + (size_t)lab * D_DIM + lane * 8);
    float s = 0.0f;
    #pragma unroll
    for (int t = 0; t < 8; ++t) s += bf2f(a[t]) * bf2f(b[t]);
    #pragma unroll
    for (int off = 32; off; off >>= 1) s += __shfl_xor(s, off);
    if (lane == 0) pos[i] = s;
}

// ---------------- fused GEMM + masked softplus reduction ----------------
// S = fN . cN^T; tile 128x128, BK=64, 4 waves (2x2), mfma 16x16x32 bf16.
// Double-buffered LDS with counted vmcnt (T4): next tile's global_load_lds
// stay in flight across the MFMA + ds_read of the current tile.
// LDS swizzle (both-sides): 16B-slot s of row r holds k-segment s ^ (r&7).
// XCD swizzle (T1): each XCD owns 8 consecutive column-tiles -> cN panel
// (1 MB) is L2-resident.
__global__ __launch_bounds__(256) void fused_loss_kernel(
        const unsigned short* __restrict__ fN, const unsigned short* __restrict__ cN,
        const int* __restrict__ labels, const float* __restrict__ pos,
        float* __restrict__ partialL, unsigned int* __restrict__ partialC) {
    __shared__ __align__(16) unsigned short As[2][128 * 64];   // 32 KB
    __shared__ __align__(16) unsigned short Bs[2][128 * 64];   // 32 KB
    __shared__ float    s_sum[4];
    __shared__ unsigned s_cnt[4];

    const int w    = threadIdx.x >> 6;
    const int lane = threadIdx.x & 63;
    const int wr   = w >> 1;          // wave row (0..1)
    const int wc   = w & 1;           // wave col (0..1)

    // XCD-aware block swizzle: dispatch-linear id -> (bx, by) such that
    // XCD k gets bx in [k*8, (k+1)*8) for all by  (2048 % 8 == 0, bijective)
    const int id = blockIdx.y * gridDim.x + blockIdx.x;
    const int v  = (id & 7) * 256 + (id >> 3);
    const int bx = v >> 5;            // 0..63  column tile
    const int by = v & 31;            // 0..31  row tile
    const int rowBase = by * 128;
    const int colBase = bx * 128;

    const int lr = lane & 15;         // frag row (A) / frag col (B)
    const int kq = lane >> 4;         // k quad

    // staging: wave w, issue q (0..3) covers tile rows w*32+q*8 .. +8
    // lane l -> row +l/8, LDS 16B-slot l%8 holding global seg (l%8)^((l/8)&7)
    const int gseg = (lane & 7) ^ ((lane >> 3) & 7);
    const unsigned short* aG =
        fN + (size_t)(rowBase + w * 32 + (lane >> 3)) * D_DIM + gseg * 8;
    const unsigned short* bG =
        cN + (size_t)(colBase + w * 32 + (lane >> 3)) * D_DIM + gseg * 8;

    f32x4 acc[4][4] = {};

#define STAGE(buf, kt)                                                        \
    do {                                                                      \
        const int K0_ = (kt) * 64;                                            \
        gload_lds16(aG + K0_ + 0 * 8 * D_DIM, &As[buf][(w * 4 + 0) * 512]);   \
        gload_lds16(aG + K0_ + 1 * 8 * D_DIM, &As[buf][(w * 4 + 1) * 512]);   \
        gload_lds16(aG + K0_ + 2 * 8 * D_DIM, &As[buf][(w * 4 + 2) * 512]);   \
        gload_lds16(aG + K0_ + 3 * 8 * D_DIM, &As[buf][(w * 4 + 3) * 512]);   \
        gload_lds16(bG + K0_ + 0 * 8 * D_DIM, &Bs[buf][(w * 4 + 0) * 512]);   \
        gload_lds16(bG + K0_ + 1 * 8 * D_DIM, &Bs[buf][(w * 4 + 1) * 512]);   \
        gload_lds16(bG + K0_ + 2 * 8 * D_DIM, &Bs[buf][(w * 4 + 2) * 512]);   \
        gload_lds16(bG + K0_ + 3 * 8 * D_DIM, &Bs[buf][(w * 4 + 3) * 512]);   \
    } while (0)

    // prologue: fill both buffers (16 loads in flight), wait for buf0 only
    STAGE(0, 0);
    STAGE(1, 1);
    asm volatile("s_waitcnt vmcnt(8)" ::: "memory");
    __builtin_amdgcn_s_barrier();

    #pragma unroll
    for (int kt = 0; kt < 8; ++kt) {
        const int cur = kt & 1;

        // ---- fragments (swizzled read): 16 x ds_read_b128 ----
        bfrag8 af[4][2], bb[4][2];
        #pragma unroll
        for (int m = 0; m < 4; ++m) {
            const int r = wr * 64 + m * 16 + lr;
            #pragma unroll
            for (int kk = 0; kk < 2; ++kk)
                af[m][kk] = *(const bfrag8*)
                    &As[cur][r * 64 + (((kk * 4 + kq) ^ (lr & 7)) * 8)];
        }
        #pragma unroll
        for (int n = 0; n < 4; ++n) {
            const int r = wc * 64 + n * 16 + lr;
            #pragma unroll
            for (int kk = 0; kk < 2; ++kk)
                bb[n][kk] = *(const bfrag8*)
                    &Bs[cur][r * 64 + (((kk * 4 + kq) ^ (lr & 7)) * 8)];
        }
        // all reads of buf[cur] done before releasing it for restage
        asm volatile("s_waitcnt lgkmcnt(0)" ::: "memory");
        __builtin_amdgcn_sched_barrier(0);
        __builtin_amdgcn_s_barrier();

        // restage the just-freed buffer with tile kt+2 (overlaps MFMA below)
        if (kt + 2 < 8) STAGE(cur, kt + 2);

        // ---- 32 MFMA ----
        #pragma unroll
        for (int kk = 0; kk < 2; ++kk)
            #pragma unroll
            for (int m = 0; m < 4; ++m)
                #pragma unroll
                for (int n = 0; n < 4; ++n)
                    acc[m][n] = __builtin_amdgcn_mfma_f32_16x16x32_bf16(
                                    af[m][kk], bb[n][kk], acc[m][n], 0, 0, 0);

        // counted wait: only require NEXT tile landed; deeper loads in flight
        if (kt < 7) {
            if (kt < 6) asm volatile("s_waitcnt vmcnt(8)" ::: "memory");
            else        asm volatile("s_waitcnt vmcnt(0)" ::: "memory");
            __builtin_amdgcn_s_barrier();
        }
    }
#undef STAGE

    // ---- epilogue: x = S_ij - pos[i]; mask j != label[i]; softplus; sum ----
    float lsum = 0.0f;
    unsigned cnt = 0;
    #pragma unroll
    for (int m = 0; m < 4; ++m) {
        #pragma unroll
        for (int j = 0; j < 4; ++j) {
            const int gi = rowBase + wr * 64 + m * 16 + kq * 4 + j;
            const float p = pos[gi];
            const int lab = labels[gi];
            #pragma unroll
            for (int n = 0; n < 4; ++n) {
                const int gj = colBase + wc * 64 + n * 16 + lr;
                const float x = acc[m][n][j] - p;
                if (gj != lab) {
                    const float l = __logf(1.0f + __expf(x));   // softplus
                    if (l > 0.0f) { lsum += l; cnt++; }
                }
            }
        }
    }
    #pragma unroll
    for (int off = 32; off; off >>= 1) {
        lsum += __shfl_xor(lsum, off);
        cnt  += __shfl_xor(cnt,  off);
    }
    if (lane == 0) { s_sum[w] = lsum; s_cnt[w] = cnt; }
    __syncthreads();
    if (threadIdx.x == 0) {
        partialL[id] = s_sum[0] + s_sum[1] + s_sum[2] + s_sum[3];
        partialC[id] = s_cnt[0] + s_cnt[1] + s_cnt[2] + s_cnt[3];
    }
}

// ---------------- finalize: reduce 2048 per-block partials ----------------
__global__ __launch_bounds__(256) void finalize_kernel(
        const float* __restrict__ partialL, const unsigned int* __restrict__ partialC,
        float* __restrict__ out) {
    __shared__ float    s_sum[4];
    __shared__ unsigned s_cnt[4];
    const int w    = threadIdx.x >> 6;
    const int lane = threadIdx.x & 63;

    float s = 0.0f; unsigned c = 0;
    for (int i = threadIdx.x; i < NBLK; i += 256) { s += partialL[i]; c += partialC[i]; }
    #pragma unroll
    for (int off = 32; off; off >>= 1) {
        s += __shfl_xor(s, off);
        c += __shfl_xor(c, off);
    }
    if (lane == 0) { s_sum[w] = s; s_cnt[w] = c; }
    __syncthreads();
    if (threadIdx.x == 0) {
        const float    l = s_sum[0] + s_sum[1] + s_sum[2] + s_sum[3];
        const unsigned n = s_cnt[0] + s_cnt[1] + s_cnt[2] + s_cnt[3];
        out[0] = (n > 0u) ? l / (float)n : l;
    }
}

extern "C" void kernel_launch(void* const* d_in, const int* in_sizes, int n_in,
                              void* d_out, int out_size, void* d_ws, size_t ws_size,
                              hipStream_t stream) {
    const float* features = (const float*)d_in[0];   // [4096, 512]
    const float* centers  = (const float*)d_in[1];   // [8192, 512]
    const int*   labels   = (const int*)d_in[2];     // [4096]
    float* out = (float*)d_out;

    char* ws = (char*)d_ws;
    unsigned short* fN  = (unsigned short*)ws;                        // 4 MB
    unsigned short* cN  = (unsigned short*)(ws + (4u << 20));         // 8 MB
    float*          pos = (float*)(ws + (12u << 20));                 // 16 KB
    float*          partialL = (float*)(ws + (12u << 20) + (1u << 16));        // 8 KB
    unsigned int*   partialC = (unsigned int*)(ws + (12u << 20) + (1u << 16) + (1u << 13)); // 8 KB

    normalize_kernel<<<N_ROWS / 4, 256, 0, stream>>>(features, fN, N_ROWS);
    normalize_kernel<<<C_ROWS / 4, 256, 0, stream>>>(centers,  cN, C_ROWS);
    posdot_kernel<<<N_ROWS / 4, 256, 0, stream>>>(fN, cN, labels, pos);

    dim3 grid(C_ROWS / 128, N_ROWS / 128);   // 64 x 32 = 2048 blocks
    fused_loss_kernel<<<grid, 256, 0, stream>>>(fN, cN, labels, pos, partialL, partialC);

    finalize_kernel<<<1, 256, 0, stream>>>(partialL, partialC, out);
}

// Round 4
// 77.288 us; speedup vs baseline: 1.3705x; 1.1071x over previous
//
#include <hip/hip_runtime.h>

#define N_ROWS 4096
#define D_DIM  512
#define C_ROWS 8192
#define BM 256
#define BN 256
#define BK 64
#define NKT (D_DIM / BK)        // 8 K-tiles
#define GX (C_ROWS / BN)        // 32
#define GY (N_ROWS / BM)        // 16
#define NBLK (GX * GY)          // 512

typedef __attribute__((ext_vector_type(8))) short bfrag8;   // 8 bf16
typedef __attribute__((ext_vector_type(4))) float f32x4;    // MFMA acc
typedef __attribute__((ext_vector_type(8))) unsigned short ushort8;

#define AS1 __attribute__((address_space(1)))
#define AS3 __attribute__((address_space(3)))

__device__ __forceinline__ void gload_lds16(const void* g, void* l) {
    __builtin_amdgcn_global_load_lds((const AS1 unsigned int*)g,
                                     (AS3 unsigned int*)l, 16, 0, 0);
}

__device__ __forceinline__ unsigned short f2bf(float f) {
    unsigned int u = __float_as_uint(f);
    unsigned int r = (u + 0x7fffu + ((u >> 16) & 1u)) >> 16;   // RNE
    return (unsigned short)r;
}
__device__ __forceinline__ float bf2f(unsigned short h) {
    return __uint_as_float(((unsigned int)h) << 16);
}

// ---------------- l2-normalize rows, fp32 -> bf16 ----------------
__global__ __launch_bounds__(256) void normalize_kernel(
        const float* __restrict__ src, unsigned short* __restrict__ dst, int rows) {
    const int w    = threadIdx.x >> 6;
    const int lane = threadIdx.x & 63;
    const int row  = blockIdx.x * 4 + w;
    if (row >= rows) return;

    const float* r = src + (size_t)row * D_DIM + lane * 8;
    float4 v0 = *(const float4*)(r);
    float4 v1 = *(const float4*)(r + 4);
    float ss = v0.x*v0.x + v0.y*v0.y + v0.z*v0.z + v0.w*v0.w
             + v1.x*v1.x + v1.y*v1.y + v1.z*v1.z + v1.w*v1.w;
    #pragma unroll
    for (int off = 32; off; off >>= 1) ss += __shfl_xor(ss, off);
    const float nrm = sqrtf(ss);
    const float sc  = 1.0f / fmaxf(nrm, 1e-12f);

    ushort8 pk;
    pk[0] = f2bf(v0.x * sc); pk[1] = f2bf(v0.y * sc);
    pk[2] = f2bf(v0.z * sc); pk[3] = f2bf(v0.w * sc);
    pk[4] = f2bf(v1.x * sc); pk[5] = f2bf(v1.y * sc);
    pk[6] = f2bf(v1.z * sc); pk[7] = f2bf(v1.w * sc);
    *(ushort8*)(dst + (size_t)row * D_DIM + lane * 8) = pk;
}

// ---------------- pos_dot[i] = fN[i] . cN[labels[i]] ----------------
__global__ __launch_bounds__(256) void posdot_kernel(
        const unsigned short* __restrict__ fN, const unsigned short* __restrict__ cN,
        const int* __restrict__ labels, float* __restrict__ pos) {
    const int w    = threadIdx.x >> 6;
    const int lane = threadIdx.x & 63;
    const int i    = blockIdx.x * 4 + w;
    const int lab  = labels[i];

    ushort8 a = *(const ushort8*)(fN + (size_t)i   * D_DIM + lane * 8);
    ushort8 b = *(const ushort8*)(cN + (size_t)lab * D_DIM + lane * 8);
    float s = 0.0f;
    #pragma unroll
    for (int t = 0; t < 8; ++t) s += bf2f(a[t]) * bf2f(b[t]);
    #pragma unroll
    for (int off = 32; off; off >>= 1) s += __shfl_xor(s, off);
    if (lane == 0) pos[i] = s;
}

// ---------------- fused GEMM + masked softplus reduction ----------------
// 256x256 tile, BK=64, 8 waves (2M x 4N, wave tile 128x64), 8-phase-style
// schedule: per K-tile 4 phases = C-quadrants (mh,nh); counted vmcnt(4);
// setprio around MFMA; LDS XOR-swizzle (slot s of row r holds seg s^(r&7)).
__global__ __launch_bounds__(512, 2) void fused_loss_kernel(
        const unsigned short* __restrict__ fN, const unsigned short* __restrict__ cN,
        const int* __restrict__ labels, const float* __restrict__ pos,
        float* __restrict__ partialL, unsigned int* __restrict__ partialC) {
    __shared__ __align__(16) unsigned short As[2][BM * BK];   // 64 KB
    __shared__ __align__(16) unsigned short Bs[2][BN * BK];   // 64 KB  (128 KB total)

    const int tid  = threadIdx.x;
    const int w    = tid >> 6;        // wave 0..7
    const int lane = tid & 63;
    const int wr   = w >> 2;          // 0..1  (M half)
    const int wn   = w & 3;           // 0..3  (N quarter)
    const int rowBase = blockIdx.y * BM;
    const int colBase = blockIdx.x * BN;

    const int lr = lane & 15;
    const int kq = lane >> 4;

    // ---- staging geometry ----
    const int rsub = lane >> 3;                 // 0..7
    const int gseg = (lane & 7) ^ rsub;         // pre-swizzled 16B k-seg
    // A issue (mh,i): tile row = mh*64 + i*128 + w*8 + rsub
    const unsigned short* aBase =
        fN + (size_t)(rowBase + w * 8 + rsub) * D_DIM + gseg * 8;
    // B issue (nh,i): tile row = i*128 + nh*32 + (w>>2)*64 + (w&3)*8 + rsub
    const unsigned short* bBase =
        cN + (size_t)(colBase + (w >> 2) * 64 + (w & 3) * 8 + rsub) * D_DIM + gseg * 8;

#define STAGE_A(buf, kt, mh, i)                                                  \
    gload_lds16(aBase + ((size_t)((mh) * 64 + (i) * 128) * D_DIM + (kt) * BK),   \
                &As[buf][((mh) * 64 + (i) * 128 + w * 8) * BK])
#define STAGE_B(buf, kt, nh, i)                                                  \
    gload_lds16(bBase + ((size_t)((i) * 128 + (nh) * 32) * D_DIM + (kt) * BK),   \
                &Bs[buf][((i) * 128 + (nh) * 32 + (w >> 2) * 64 + (w & 3) * 8) * BK])
#define CHUNK_A(buf, kt, mh) do { STAGE_A(buf, kt, mh, 0); STAGE_A(buf, kt, mh, 1); } while (0)
#define CHUNK_B(buf, kt, nh) do { STAGE_B(buf, kt, nh, 0); STAGE_B(buf, kt, nh, 1); } while (0)

    // swizzled fragment reads (row r: slot of k-seg g is g ^ (r&7); r&7 == lr&7)
#define READ_A(dst, b, m, kk)                                                    \
    dst = *(const bfrag8*)&As[b][(wr * 128 + (m) * 16 + lr) * BK +               \
                                 ((((kk) * 4 + kq) ^ (lr & 7)) * 8)]
#define READ_B(dst, b, n, kk)                                                    \
    dst = *(const bfrag8*)&Bs[b][(wn * 64 + (n) * 16 + lr) * BK +                \
                                 ((((kk) * 4 + kq) ^ (lr & 7)) * 8)]

    f32x4 acc[8][4] = {};
    bfrag8 af[4][2];        // current M-half A frags [m4][kk]
    bfrag8 bb[2][2][2];     // B frags [nh][n2][kk]

    // prologue: stage tile 0 in steady-state chunk order A0,B0,B1,A1
    CHUNK_A(0, 0, 0); CHUNK_B(0, 0, 0); CHUNK_B(0, 0, 1); CHUNK_A(0, 0, 1);

    #pragma unroll
    for (int t = 0; t < NKT; ++t) {
        const int b  = t & 1;
        const int nb = b ^ 1;
        const bool pf = (t + 1 < NKT);

        // ---------- P0: quadrant (mh=0, nh=0); needs chunks A0,B0 ----------
        asm volatile("s_waitcnt vmcnt(4)" ::: "memory");
        __builtin_amdgcn_s_barrier();
        #pragma unroll
        for (int m4 = 0; m4 < 4; ++m4) { READ_A(af[m4][0], b, m4, 0); READ_A(af[m4][1], b, m4, 1); }
        #pragma unroll
        for (int n2 = 0; n2 < 2; ++n2) { READ_B(bb[0][n2][0], b, n2, 0); READ_B(bb[0][n2][1], b, n2, 1); }
        if (pf) CHUNK_A(nb, t + 1, 0);
        asm volatile("s_waitcnt lgkmcnt(0)" ::: "memory");
        __builtin_amdgcn_sched_barrier(0);
        __builtin_amdgcn_s_setprio(1);
        #pragma unroll
        for (int kk = 0; kk < 2; ++kk)
            #pragma unroll
            for (int m4 = 0; m4 < 4; ++m4)
                #pragma unroll
                for (int n2 = 0; n2 < 2; ++n2)
                    acc[m4][n2] = __builtin_amdgcn_mfma_f32_16x16x32_bf16(
                                      af[m4][kk], bb[0][n2][kk], acc[m4][n2], 0, 0, 0);
        __builtin_amdgcn_s_setprio(0);

        // ---------- P1: quadrant (mh=0, nh=1); needs chunk B1 ----------
        if (pf) asm volatile("s_waitcnt vmcnt(4)" ::: "memory");
        else    asm volatile("s_waitcnt vmcnt(2)" ::: "memory");
        __builtin_amdgcn_s_barrier();
        #pragma unroll
        for (int n2 = 0; n2 < 2; ++n2) { READ_B(bb[1][n2][0], b, 2 + n2, 0); READ_B(bb[1][n2][1], b, 2 + n2, 1); }
        if (pf) CHUNK_B(nb, t + 1, 0);
        asm volatile("s_waitcnt lgkmcnt(0)" ::: "memory");
        __builtin_amdgcn_sched_barrier(0);
        __builtin_amdgcn_s_setprio(1);
        #pragma unroll
        for (int kk = 0; kk < 2; ++kk)
            #pragma unroll
            for (int m4 = 0; m4 < 4; ++m4)
                #pragma unroll
                for (int n2 = 0; n2 < 2; ++n2)
                    acc[m4][2 + n2] = __builtin_amdgcn_mfma_f32_16x16x32_bf16(
                                          af[m4][kk], bb[1][n2][kk], acc[m4][2 + n2], 0, 0, 0);
        __builtin_amdgcn_s_setprio(0);

        // ---------- P2: quadrant (mh=1, nh=0); needs chunk A1 ----------
        if (pf) asm volatile("s_waitcnt vmcnt(4)" ::: "memory");
        else    asm volatile("s_waitcnt vmcnt(0)" ::: "memory");
        __builtin_amdgcn_s_barrier();
        #pragma unroll
        for (int m4 = 0; m4 < 4; ++m4) { READ_A(af[m4][0], b, 4 + m4, 0); READ_A(af[m4][1], b, 4 + m4, 1); }
        if (pf) CHUNK_B(nb, t + 1, 1);
        asm volatile("s_waitcnt lgkmcnt(0)" ::: "memory");
        __builtin_amdgcn_sched_barrier(0);
        __builtin_amdgcn_s_setprio(1);
        #pragma unroll
        for (int kk = 0; kk < 2; ++kk)
            #pragma unroll
            for (int m4 = 0; m4 < 4; ++m4)
                #pragma unroll
                for (int n2 = 0; n2 < 2; ++n2)
                    acc[4 + m4][n2] = __builtin_amdgcn_mfma_f32_16x16x32_bf16(
                                          af[m4][kk], bb[0][n2][kk], acc[4 + m4][n2], 0, 0, 0);
        __builtin_amdgcn_s_setprio(0);

        // ---------- P3: quadrant (mh=1, nh=1); no new reads, no barrier ----------
        if (pf) CHUNK_A(nb, t + 1, 1);
        __builtin_amdgcn_s_setprio(1);
        #pragma unroll
        for (int kk = 0; kk < 2; ++kk)
            #pragma unroll
            for (int m4 = 0; m4 < 4; ++m4)
                #pragma unroll
                for (int n2 = 0; n2 < 2; ++n2)
                    acc[4 + m4][2 + n2] = __builtin_amdgcn_mfma_f32_16x16x32_bf16(
                                              af[m4][kk], bb[1][n2][kk], acc[4 + m4][2 + n2], 0, 0, 0);
        __builtin_amdgcn_s_setprio(0);
    }

#undef STAGE_A
#undef STAGE_B
#undef CHUNK_A
#undef CHUNK_B
#undef READ_A
#undef READ_B

    // ---- epilogue: x = S_ij - pos[i]; mask j != label[i]; softplus; sum ----
    float lsum = 0.0f;
    unsigned cnt = 0;
    #pragma unroll
    for (int m = 0; m < 8; ++m) {
        #pragma unroll
        for (int j = 0; j < 4; ++j) {
            const int gi = rowBase + wr * 128 + m * 16 + kq * 4 + j;
            const float p = pos[gi];
            const int lab = labels[gi];
            #pragma unroll
            for (int n = 0; n < 4; ++n) {
                const int gj = colBase + wn * 64 + n * 16 + lr;
                const float x = acc[m][n][j] - p;
                if (gj != lab) {
                    const float l = __logf(1.0f + __expf(x));   // softplus
                    if (l > 0.0f) { lsum += l; cnt++; }
                }
            }
        }
    }
    #pragma unroll
    for (int off = 32; off; off >>= 1) {
        lsum += __shfl_xor(lsum, off);
        cnt  += __shfl_xor(cnt,  off);
    }

    __syncthreads();                        // safe to reuse LDS
    float*    s_sum = (float*)&As[0][0];
    unsigned* s_cnt = (unsigned*)&As[0][64];
    if (lane == 0) { s_sum[w] = lsum; s_cnt[w] = cnt; }
    __syncthreads();
    if (tid == 0) {
        float    L = 0.0f;
        unsigned C = 0;
        #pragma unroll
        for (int i = 0; i < 8; ++i) { L += s_sum[i]; C += s_cnt[i]; }
        const int id = blockIdx.y * gridDim.x + blockIdx.x;
        partialL[id] = L;
        partialC[id] = C;
    }
}

// ---------------- finalize: reduce 512 per-block partials ----------------
__global__ __launch_bounds__(256) void finalize_kernel(
        const float* __restrict__ partialL, const unsigned int* __restrict__ partialC,
        float* __restrict__ out) {
    __shared__ float    s_sum[4];
    __shared__ unsigned s_cnt[4];
    const int w    = threadIdx.x >> 6;
    const int lane = threadIdx.x & 63;

    float s = 0.0f; unsigned c = 0;
    for (int i = threadIdx.x; i < NBLK; i += 256) { s += partialL[i]; c += partialC[i]; }
    #pragma unroll
    for (int off = 32; off; off >>= 1) {
        s += __shfl_xor(s, off);
        c += __shfl_xor(c, off);
    }
    if (lane == 0) { s_sum[w] = s; s_cnt[w] = c; }
    __syncthreads();
    if (threadIdx.x == 0) {
        const float    l = s_sum[0] + s_sum[1] + s_sum[2] + s_sum[3];
        const unsigned n = s_cnt[0] + s_cnt[1] + s_cnt[2] + s_cnt[3];
        out[0] = (n > 0u) ? l / (float)n : l;
    }
}

extern "C" void kernel_launch(void* const* d_in, const int* in_sizes, int n_in,
                              void* d_out, int out_size, void* d_ws, size_t ws_size,
                              hipStream_t stream) {
    const float* features = (const float*)d_in[0];   // [4096, 512]
    const float* centers  = (const float*)d_in[1];   // [8192, 512]
    const int*   labels   = (const int*)d_in[2];     // [4096]
    float* out = (float*)d_out;

    char* ws = (char*)d_ws;
    unsigned short* fN  = (unsigned short*)ws;                        // 4 MB
    unsigned short* cN  = (unsigned short*)(ws + (4u << 20));         // 8 MB
    float*          pos = (float*)(ws + (12u << 20));                 // 16 KB
    float*          partialL = (float*)(ws + (12u << 20) + (1u << 16));
    unsigned int*   partialC = (unsigned int*)(ws + (12u << 20) + (1u << 16) + (1u << 13));

    normalize_kernel<<<N_ROWS / 4, 256, 0, stream>>>(features, fN, N_ROWS);
    normalize_kernel<<<C_ROWS / 4, 256, 0, stream>>>(centers,  cN, C_ROWS);
    posdot_kernel<<<N_ROWS / 4, 256, 0, stream>>>(fN, cN, labels, pos);

    dim3 grid(GX, GY);   // 32 x 16 = 512 blocks, 512 threads
    fused_loss_kernel<<<grid, 512, 0, stream>>>(fN, cN, labels, pos, partialL, partialC);

    finalize_kernel<<<1, 256, 0, stream>>>(partialL, partialC, out);
}